// Round 5
// baseline (225.240 us; speedup 1.0000x reference)
//
#include <hip/hip_runtime.h>

typedef unsigned short u16;
typedef __bf16 bf16x8 __attribute__((ext_vector_type(8)));
typedef float f32x4 __attribute__((ext_vector_type(4)));
typedef unsigned short u16x8 __attribute__((ext_vector_type(8)));

#define QKV_N 5120
#define SEQ 2048
#define ATTN_K 4096
#define KPAD 2944   // 2880 padded to 46*64
#define SCALE 0.125f
#define NEGINF -1e30f

__device__ __forceinline__ u16 f2bf(float f) {
  unsigned int u = __builtin_bit_cast(unsigned int, f);
  u = (u + 0x7FFFu + ((u >> 16) & 1u)) >> 16;
  return (u16)u;
}

#define MFMA16(a, b, c) __builtin_amdgcn_mfma_f32_16x16x32_bf16((a), (b), (c), 0, 0, 0)

// async global->LDS, 16B per lane; LDS dest = wave-uniform base + lane*16
__device__ __forceinline__ void gl_lds16(const u16* g, u16* l) {
  __builtin_amdgcn_global_load_lds(
      (const __attribute__((address_space(1))) unsigned int*)(const void*)g,
      (__attribute__((address_space(3))) unsigned int*)(void*)l, 16, 0, 0);
}

// read a bf16x8 fragment from a swizzled [rows][64] bf16 LDS tile (128 B/row)
__device__ __forceinline__ bf16x8 lds_frag(const u16* mat, int row, int kh, int lg) {
  int off = row * 128 + ((kh * 64 + lg * 16) ^ ((row & 7) << 4));
  return *(const bf16x8*)((const char*)mat + off);
}

// ---------------- RoPE table: tab[s*32+i] = {cos, sin} ----------------
__global__ __launch_bounds__(256) void k_rope_table(const int* __restrict__ pos,
                                                    float2* __restrict__ tab) {
  int t = blockIdx.x * 256 + threadIdx.x;  // 65536 = 2048*32
  int s = t >> 5, i = t & 31;
  float freq = powf(150000.0f, -(float)i * (1.0f / 32.0f));
  float ang = (float)pos[s] * freq;
  float sv, cv;
  sincosf(ang, &sv, &cv);
  tab[t] = make_float2(cv, sv);
}

// ---------------- f32 -> bf16 convert with K-pad: out [2048][2944] ----------------
__global__ __launch_bounds__(256) void k_convert_pad(const float* __restrict__ in,
                                                     u16* __restrict__ out) {
  int i = blockIdx.x * 256 + threadIdx.x;  // per 4 out elems; 2048*736 total
  int r = i / 736, c4 = i - r * 736;
  if (r >= 2048) return;
  ushort4 o = {0, 0, 0, 0};
  if (c4 < 720) {
    float4 v = *(const float4*)(in + (size_t)r * 2880 + c4 * 4);
    o.x = f2bf(v.x); o.y = f2bf(v.y); o.z = f2bf(v.z); o.w = f2bf(v.w);
  }
  ((ushort4*)out)[(size_t)r * 736 + c4] = o;
}

// ------ transpose+convert: in f32 [Kin][Nd] -> out bf16 [Npad][Kout], zero-padded ------
__global__ __launch_bounds__(256) void k_transpose(const float* __restrict__ in,
                                                   u16* __restrict__ out,
                                                   int Kin, int Kout, int Nd, int Npad) {
  __shared__ float tile[32][33];
  int n0 = blockIdx.x * 32, k0 = blockIdx.y * 32;
  int c = threadIdx.x & 31, r0 = threadIdx.x >> 5;
#pragma unroll
  for (int j = 0; j < 4; j++) {
    int r = r0 + j * 8;
    float v = 0.f;
    if (n0 + c < Nd && k0 + r < Kin) v = in[(size_t)(k0 + r) * Nd + n0 + c];
    tile[r][c] = v;
  }
  __syncthreads();
#pragma unroll
  for (int j = 0; j < 4; j++) {
    int rr = r0 + j * 8;  // local n
    int n = n0 + rr;
    if (n < Npad) out[(size_t)n * Kout + k0 + c] = f2bf(tile[c][rr]);
  }
}

// ======== GEMM1: 256x256, BK=64, 2-tile ring, counted vmcnt, NO intra-tile barriers ====
// A [2048][2944] bf16, B [5120][2944] bf16 (B^T), out qkv bf16 [2048][5120].
// Per K-tile: ds_reads pipelined ahead of MFMA quads (reg double-buffer); 2 barriers/tile.
__global__ __launch_bounds__(512, 1) void k_gemm1(const u16* __restrict__ Ag,
                                                  const u16* __restrict__ Bg,
                                                  const float* __restrict__ bias,
                                                  const float2* __restrict__ tab,
                                                  u16* __restrict__ C) {
  __shared__ u16 ldsbuf[2][32768];  // [buf][A 16384 u16 | B 16384 u16]
  const int tid = threadIdx.x;
  const int lane = tid & 63, wave = tid >> 6;
  const int wm = wave >> 2, wn = wave & 3;
  const int lr = lane & 15, lg = lane >> 4;
  int bid = blockIdx.x;
  int sb = (bid & 7) * 20 + (bid >> 3);  // 160 = 8 XCD x 20
  const int m0 = (sb / 20) * 256, n0 = (sb % 20) * 256;

  f32x4 acc[8][4] = {};

  const int srow = wave * 8 + (lane >> 3);            // within 64-row round
  const int sc = ((lane & 7) ^ (lane >> 3)) << 3;     // pre-swizzled chunk (elems)
  const u16* gA = Ag + (size_t)(m0 + srow) * KPAD + sc;
  const u16* gB = Bg + (size_t)(n0 + srow) * KPAD + sc;

#define G1_STAGE(kt, b)                                                          \
  {                                                                              \
    u16* Ab = &ldsbuf[b][0];                                                     \
    u16* Bb = &ldsbuf[b][16384];                                                 \
    _Pragma("unroll") for (int r = 0; r < 4; r++) {                              \
      gl_lds16(gA + (size_t)(r * 64) * KPAD + (kt), Ab + (r * 64 + wave * 8) * 64); \
      gl_lds16(gB + (size_t)(r * 64) * KPAD + (kt), Bb + (r * 64 + wave * 8) * 64); \
    }                                                                            \
  }

  // prologue: T0 -> buf0, T1 -> buf1; certify T0 (8 newest stay in flight)
  G1_STAGE(0, 0)
  G1_STAGE(64, 1)
  asm volatile("s_waitcnt vmcnt(8)" ::: "memory");
  __builtin_amdgcn_s_barrier();

  for (int t = 0; t < 46; t++) {
    const int b = t & 1;
    const u16* La = &ldsbuf[b][0];
    const u16* Lb = &ldsbuf[b][16384];
    // tile-entry reads: all B frags + A quad 0
    bf16x8 Bf[4][2];
#pragma unroll
    for (int nf = 0; nf < 4; nf++)
#pragma unroll
      for (int kh = 0; kh < 2; kh++)
        Bf[nf][kh] = lds_frag(Lb, wn * 64 + nf * 16 + lr, kh, lg);
    bf16x8 Af[2][2];
#pragma unroll
    for (int mi = 0; mi < 2; mi++)
#pragma unroll
      for (int kh = 0; kh < 2; kh++)
        Af[mi][kh] = lds_frag(La, wm * 128 + mi * 16 + lr, kh, lg);
    // quads: prefetch q+1's A frags, then MFMA quad q (no barriers between)
#pragma unroll
    for (int q = 0; q < 4; q++) {
      bf16x8 An[2][2];
      if (q < 3) {
#pragma unroll
        for (int mi = 0; mi < 2; mi++)
#pragma unroll
          for (int kh = 0; kh < 2; kh++)
            An[mi][kh] = lds_frag(La, wm * 128 + ((q + 1) * 2 + mi) * 16 + lr, kh, lg);
      }
      __builtin_amdgcn_s_setprio(1);
#pragma unroll
      for (int mi = 0; mi < 2; mi++)
#pragma unroll
        for (int nf = 0; nf < 4; nf++)
#pragma unroll
          for (int kh = 0; kh < 2; kh++)
            acc[q * 2 + mi][nf] = MFMA16(Af[mi][kh], Bf[nf][kh], acc[q * 2 + mi][nf]);
      __builtin_amdgcn_s_setprio(0);
      if (q < 3) {
#pragma unroll
        for (int mi = 0; mi < 2; mi++)
#pragma unroll
          for (int kh = 0; kh < 2; kh++)
            Af[mi][kh] = An[mi][kh];
      }
    }
    __builtin_amdgcn_s_barrier();  // all waves consumed buf[b]
    if (t <= 43) {
      G1_STAGE((t + 2) * 64, b)
      asm volatile("s_waitcnt vmcnt(8)" ::: "memory");  // t+1 resident; t+2 in flight
    } else {
      asm volatile("s_waitcnt vmcnt(0)" ::: "memory");
    }
    __builtin_amdgcn_s_barrier();  // buf[b^1] certified for tile t+1
  }
#undef G1_STAGE

  // ---- epilogue: bias (+ RoPE for Q/K cols), bf16 store ----
  const bool rope = (n0 < 4608);
  if (rope) {
#pragma unroll
    for (int mf = 0; mf < 8; mf++)
#pragma unroll
      for (int nf = 0; nf < 2; nf++) {
        int col1 = n0 + wn * 64 + nf * 16 + lr;
        int col2 = col1 + 32;
        float b1 = bias[col1], b2 = bias[col2];
#pragma unroll
        for (int rg = 0; rg < 4; rg++) {
          int row = m0 + wm * 128 + mf * 16 + lg * 4 + rg;
          float2 cs = tab[(size_t)row * 32 + nf * 16 + lr];
          float x1 = acc[mf][nf][rg] + b1;
          float x2 = acc[mf][nf + 2][rg] + b2;
          C[(size_t)row * QKV_N + col1] = f2bf(x1 * cs.x - x2 * cs.y);
          C[(size_t)row * QKV_N + col2] = f2bf(x2 * cs.x + x1 * cs.y);
        }
      }
  } else {
#pragma unroll
    for (int mf = 0; mf < 8; mf++)
#pragma unroll
      for (int nf = 0; nf < 4; nf++) {
        int col = n0 + wn * 64 + nf * 16 + lr;
        float bv = bias[col];
#pragma unroll
        for (int rg = 0; rg < 4; rg++) {
          int row = m0 + wm * 128 + mf * 16 + lg * 4 + rg;
          C[(size_t)row * QKV_N + col] = f2bf(acc[mf][nf][rg] + bv);
        }
      }
  }
}

// ======== GEMM2: 128x128, BK=64, 2-tile ring, counted vmcnt, no intra-tile barriers ====
// A = attn bf16 [2048][4096], B = woT bf16 [2944][4096], C f32 [2048][2880].
__global__ __launch_bounds__(256, 2) void k_gemm2(const u16* __restrict__ Ag,
                                                  const u16* __restrict__ Bg,
                                                  const float* __restrict__ bias,
                                                  float* __restrict__ C) {
  __shared__ u16 ldsbuf[2][16384];  // [buf][A 8192 | B 8192]
  const int tid = threadIdx.x;
  const int lane = tid & 63, wave = tid >> 6;
  const int wm = wave >> 1, wn = wave & 1;
  const int lr = lane & 15, lg = lane >> 4;
  int bid = blockIdx.x;
  int sb = (bid & 7) * 46 + (bid >> 3);  // 368 = 8 XCD x 46
  const int m0 = (sb / 23) * 128, n0 = (sb % 23) * 128;

  f32x4 acc[4][4] = {};

  const int srow = wave * 8 + (lane >> 3);         // within 32-row round
  const int sc = ((lane & 7) ^ (lane >> 3)) << 3;  // pre-swizzled chunk
  const u16* gA = Ag + (size_t)(m0 + srow) * ATTN_K + sc;
  const u16* gB = Bg + (size_t)(n0 + srow) * ATTN_K + sc;

#define G2_STAGE(kt, b)                                                          \
  {                                                                              \
    u16* Ab = &ldsbuf[b][0];                                                     \
    u16* Bb = &ldsbuf[b][8192];                                                  \
    _Pragma("unroll") for (int r = 0; r < 4; r++) {                              \
      gl_lds16(gA + (size_t)(r * 32) * ATTN_K + (kt), Ab + (r * 32 + wave * 8) * 64); \
      gl_lds16(gB + (size_t)(r * 32) * ATTN_K + (kt), Bb + (r * 32 + wave * 8) * 64); \
    }                                                                            \
  }

  G2_STAGE(0, 0)
  G2_STAGE(64, 1)
  asm volatile("s_waitcnt vmcnt(8)" ::: "memory");
  __builtin_amdgcn_s_barrier();

  for (int t = 0; t < 64; t++) {
    const int b = t & 1;
    const u16* La = &ldsbuf[b][0];
    const u16* Lb = &ldsbuf[b][8192];
    bf16x8 Bf[4][2];
#pragma unroll
    for (int nf = 0; nf < 4; nf++)
#pragma unroll
      for (int kh = 0; kh < 2; kh++)
        Bf[nf][kh] = lds_frag(Lb, wn * 64 + nf * 16 + lr, kh, lg);
    bf16x8 Af[2][2];
#pragma unroll
    for (int mi = 0; mi < 2; mi++)
#pragma unroll
      for (int kh = 0; kh < 2; kh++)
        Af[mi][kh] = lds_frag(La, wm * 64 + mi * 16 + lr, kh, lg);
#pragma unroll
    for (int q = 0; q < 2; q++) {
      bf16x8 An[2][2];
      if (q < 1) {
#pragma unroll
        for (int mi = 0; mi < 2; mi++)
#pragma unroll
          for (int kh = 0; kh < 2; kh++)
            An[mi][kh] = lds_frag(La, wm * 64 + ((q + 1) * 2 + mi) * 16 + lr, kh, lg);
      }
      __builtin_amdgcn_s_setprio(1);
#pragma unroll
      for (int mi = 0; mi < 2; mi++)
#pragma unroll
        for (int nf = 0; nf < 4; nf++)
#pragma unroll
          for (int kh = 0; kh < 2; kh++)
            acc[q * 2 + mi][nf] = MFMA16(Af[mi][kh], Bf[nf][kh], acc[q * 2 + mi][nf]);
      __builtin_amdgcn_s_setprio(0);
      if (q < 1) {
#pragma unroll
        for (int mi = 0; mi < 2; mi++)
#pragma unroll
          for (int kh = 0; kh < 2; kh++)
            Af[mi][kh] = An[mi][kh];
      }
    }
    __builtin_amdgcn_s_barrier();
    if (t <= 61) {
      G2_STAGE((t + 2) * 64, b)
      asm volatile("s_waitcnt vmcnt(8)" ::: "memory");
    } else {
      asm volatile("s_waitcnt vmcnt(0)" ::: "memory");
    }
    __builtin_amdgcn_s_barrier();
  }
#undef G2_STAGE

#pragma unroll
  for (int mi = 0; mi < 4; mi++)
#pragma unroll
    for (int ni = 0; ni < 4; ni++) {
      int row = m0 + wm * 64 + mi * 16 + lg * 4;
      int col = n0 + wn * 64 + ni * 16 + lr;
      if (col < 2880) {
        float bv = bias[col];
#pragma unroll
        for (int rg = 0; rg < 4; rg++)
          C[(size_t)(row + rg) * 2880 + col] = acc[mi][ni][rg] + bv;
      }
    }
}

// ---------------- sliding-window attention with sinks (bf16 qkv input) ----------------
__global__ __launch_bounds__(512, 2) void k_attn(const u16* __restrict__ qkv,
                                                 const float* __restrict__ sinks,
                                                 u16* __restrict__ out) {
  __shared__ u16 Klds[160 * 64];
  __shared__ u16 Vt[64 * 168];
  __shared__ u16 Pslab[8 * 32 * 40];
  const int hk = blockIdx.y;
  const int s0 = blockIdx.x * 32;
  const int kb = s0 - 127;
  const int tid = threadIdx.x;
  const int lane = tid & 63, w = tid >> 6;
  const int lr = lane & 15, lg = lane >> 4;

  for (int ch = tid; ch < 160 * 8; ch += 512) {
    int key = ch >> 3, c = ch & 7;
    int kidx = kb + key;
    u16x8 val = {0, 0, 0, 0, 0, 0, 0, 0};
    if (kidx >= 0 && kidx < SEQ)
      val = *(const u16x8*)(qkv + (size_t)kidx * QKV_N + 4096 + hk * 64 + c * 8);
    int off = (key * 128 + c * 16) ^ ((key & 7) << 4);
    *(u16x8*)((char*)Klds + off) = val;
  }
  for (int e4 = tid; e4 < 160 * 16; e4 += 512) {
    int key = e4 >> 4, d0 = (e4 & 15) * 4;
    int kidx = kb + key;
    ushort4 v = {0, 0, 0, 0};
    if (kidx >= 0 && kidx < SEQ)
      v = *(const ushort4*)(qkv + (size_t)kidx * QKV_N + 4608 + hk * 64 + d0);
    Vt[(d0 + 0) * 168 + key] = v.x;
    Vt[(d0 + 1) * 168 + key] = v.y;
    Vt[(d0 + 2) * 168 + key] = v.z;
    Vt[(d0 + 3) * 168 + key] = v.w;
  }

  const int head = hk * 8 + w;
  bf16x8 qf[2][2];
#pragma unroll
  for (int rt = 0; rt < 2; rt++)
#pragma unroll
    for (int ks = 0; ks < 2; ks++)
      qf[rt][ks] = *(const bf16x8*)(qkv + (size_t)(s0 + rt * 16 + lr) * QKV_N +
                                    head * 64 + ks * 32 + lg * 8);
  __syncthreads();

  f32x4 sc[2][10];
  f32x4 zz = {0.f, 0.f, 0.f, 0.f};
#pragma unroll
  for (int rt = 0; rt < 2; rt++)
#pragma unroll
    for (int nt = 0; nt < 10; nt++) sc[rt][nt] = zz;
#pragma unroll
  for (int nt = 0; nt < 10; nt++) {
    int key = nt * 16 + lr;
#pragma unroll
    for (int ks = 0; ks < 2; ks++) {
      int off = (key * 128 + ks * 64 + lg * 16) ^ ((key & 7) << 4);
      bf16x8 kf = *(const bf16x8*)((const char*)Klds + off);
      sc[0][nt] = MFMA16(qf[0][ks], kf, sc[0][nt]);
      sc[1][nt] = MFMA16(qf[1][ks], kf, sc[1][nt]);
    }
  }

#pragma unroll
  for (int rt = 0; rt < 2; rt++)
#pragma unroll
    for (int nt = 0; nt < 10; nt++)
#pragma unroll
      for (int rg = 0; rg < 4; rg++) {
        int qq = rt * 16 + lg * 4 + rg;
        int j = nt * 16 + lr;
        bool valid = (j >= qq) && (j <= qq + 127) && ((kb + j) >= 0);
        sc[rt][nt][rg] = valid ? sc[rt][nt][rg] * SCALE : NEGINF;
      }

  const float sink = sinks[head];
  float den[2][4];
#pragma unroll
  for (int rt = 0; rt < 2; rt++)
#pragma unroll
    for (int rg = 0; rg < 4; rg++) {
      float m = NEGINF;
#pragma unroll
      for (int nt = 0; nt < 10; nt++) m = fmaxf(m, sc[rt][nt][rg]);
#pragma unroll
      for (int x = 1; x < 16; x <<= 1) m = fmaxf(m, __shfl_xor(m, x, 64));
      m = fmaxf(m, sink);
      float sum = 0.f;
#pragma unroll
      for (int nt = 0; nt < 10; nt++) {
        float p = __expf(sc[rt][nt][rg] - m);
        sc[rt][nt][rg] = p;
        sum += p;
      }
#pragma unroll
      for (int x = 1; x < 16; x <<= 1) sum += __shfl_xor(sum, x, 64);
      den[rt][rg] = sum + __expf(sink - m);
    }

  f32x4 oacc[2][4];
#pragma unroll
  for (int rt = 0; rt < 2; rt++)
#pragma unroll
    for (int dn = 0; dn < 4; dn++) oacc[rt][dn] = zz;
  u16* slab = &Pslab[w * 32 * 40];
#pragma unroll
  for (int kt = 0; kt < 5; kt++) {
#pragma unroll
    for (int rt = 0; rt < 2; rt++)
#pragma unroll
      for (int j2 = 0; j2 < 2; j2++)
#pragma unroll
        for (int rg = 0; rg < 4; rg++)
          slab[(rt * 16 + lg * 4 + rg) * 40 + j2 * 16 + lr] = f2bf(sc[rt][kt * 2 + j2][rg]);
    asm volatile("s_waitcnt lgkmcnt(0)" ::: "memory");
    __builtin_amdgcn_sched_barrier(0);
    bf16x8 pf0 = *(const bf16x8*)&slab[lr * 40 + lg * 8];
    bf16x8 pf1 = *(const bf16x8*)&slab[(16 + lr) * 40 + lg * 8];
#pragma unroll
    for (int dn = 0; dn < 4; dn++) {
      bf16x8 vf = *(const bf16x8*)&Vt[(dn * 16 + lr) * 168 + kt * 32 + lg * 8];
      oacc[0][dn] = MFMA16(pf0, vf, oacc[0][dn]);
      oacc[1][dn] = MFMA16(pf1, vf, oacc[1][dn]);
    }
  }

#pragma unroll
  for (int rt = 0; rt < 2; rt++)
#pragma unroll
    for (int dn = 0; dn < 4; dn++)
#pragma unroll
      for (int rg = 0; rg < 4; rg++) {
        int s = s0 + rt * 16 + lg * 4 + rg;
        float val = oacc[rt][dn][rg] / den[rt][rg];
        out[(size_t)s * ATTN_K + head * 64 + dn * 16 + lr] = f2bf(val);
      }
}

extern "C" void kernel_launch(void* const* d_in, const int* in_sizes, int n_in,
                              void* d_out, int out_size, void* d_ws, size_t ws_size,
                              hipStream_t stream) {
  const float* hs = (const float*)d_in[0];
  const int* pos = (const int*)d_in[1];
  const float* wqkv = (const float*)d_in[2];
  const float* bqkv = (const float*)d_in[3];
  const float* wo = (const float*)d_in[4];
  const float* bo = (const float*)d_in[5];
  const float* sinks = (const float*)d_in[6];
  float* out = (float*)d_out;

  char* ws = (char*)d_ws;
  u16* qkvb = (u16*)(ws + 0);               // 2048*5120*2 = 20,971,520 (bf16)
  u16* hsb = (u16*)(ws + 41943040);         // 2048*2944*2 = 12,058,624
  u16* wqkvT = (u16*)(ws + 54001664);       // 5120*2944*2 = 30,146,560 -> ends 84,148,224
  u16* attnb = (u16*)(ws + 41943040);       // 2048*4096*2 (aliases dead hsb/wqkvT)
  u16* woT = (u16*)(ws + 84148224);         // 2944*4096*2 = 24,117,248 -> ends 108,265,472
  float2* tab = (float2*)(ws + 108265472);  // 2048*32*8   = 524,288

  k_rope_table<<<256, 256, 0, stream>>>(pos, tab);
  k_convert_pad<<<5888, 256, 0, stream>>>(hs, hsb);
  k_transpose<<<dim3(160, 92), 256, 0, stream>>>(wqkv, wqkvT, 2880, KPAD, 5120, 5120);
  k_transpose<<<dim3(92, 128), 256, 0, stream>>>(wo, woT, 4096, 4096, 2880, 2944);
  k_gemm1<<<160, 512, 0, stream>>>(hsb, wqkvT, bqkv, tab, qkvb);
  k_attn<<<dim3(64, 8), 512, 0, stream>>>(qkvb, sinks, attnb);
  k_gemm2<<<368, 256, 0, stream>>>(attnb, woT, bo, out);
}

// Round 6
// 210.275 us; speedup vs baseline: 1.0712x; 1.0712x over previous
//
#include <hip/hip_runtime.h>

typedef unsigned short u16;
typedef __bf16 bf16x8 __attribute__((ext_vector_type(8)));
typedef float f32x4 __attribute__((ext_vector_type(4)));
typedef unsigned short u16x8 __attribute__((ext_vector_type(8)));

#define QKV_N 5120
#define SEQ 2048
#define ATTN_K 4096
#define KPAD 2944   // 2880 padded to 46*64
#define SCALE 0.125f
#define NEGINF -1e30f

__device__ __forceinline__ u16 f2bf(float f) {
  unsigned int u = __builtin_bit_cast(unsigned int, f);
  u = (u + 0x7FFFu + ((u >> 16) & 1u)) >> 16;
  return (u16)u;
}

#define MFMA16(a, b, c) __builtin_amdgcn_mfma_f32_16x16x32_bf16((a), (b), (c), 0, 0, 0)

// async global->LDS, 16B per lane; LDS dest = wave-uniform base + lane*16
__device__ __forceinline__ void gl_lds16(const u16* g, u16* l) {
  __builtin_amdgcn_global_load_lds(
      (const __attribute__((address_space(1))) unsigned int*)(const void*)g,
      (__attribute__((address_space(3))) unsigned int*)(void*)l, 16, 0, 0);
}

// fragment read from [rows][32k] half-tile (64B rows), swizzle byte ^= (row&3)<<4
__device__ __forceinline__ bf16x8 fragrd(const u16* base, int row, int rb) {
  return *(const bf16x8*)((const char*)(base + row * 32) + rb);
}

// legacy frag read for GEMM2's [rows][64k] swizzled tile (128B rows)
__device__ __forceinline__ bf16x8 lds_frag(const u16* mat, int row, int kh, int lg) {
  int off = row * 128 + ((kh * 64 + lg * 16) ^ ((row & 7) << 4));
  return *(const bf16x8*)((const char*)mat + off);
}

// ---------------- RoPE table: tab[s*32+i] = {cos, sin} ----------------
__global__ __launch_bounds__(256) void k_rope_table(const int* __restrict__ pos,
                                                    float2* __restrict__ tab) {
  int t = blockIdx.x * 256 + threadIdx.x;  // 65536 = 2048*32
  int s = t >> 5, i = t & 31;
  float freq = powf(150000.0f, -(float)i * (1.0f / 32.0f));
  float ang = (float)pos[s] * freq;
  float sv, cv;
  sincosf(ang, &sv, &cv);
  tab[t] = make_float2(cv, sv);
}

// ---------------- f32 -> bf16 convert with K-pad: out [2048][2944] ----------------
__global__ __launch_bounds__(256) void k_convert_pad(const float* __restrict__ in,
                                                     u16* __restrict__ out) {
  int i = blockIdx.x * 256 + threadIdx.x;  // per 4 out elems; 2048*736 total
  int r = i / 736, c4 = i - r * 736;
  if (r >= 2048) return;
  ushort4 o = {0, 0, 0, 0};
  if (c4 < 720) {
    float4 v = *(const float4*)(in + (size_t)r * 2880 + c4 * 4);
    o.x = f2bf(v.x); o.y = f2bf(v.y); o.z = f2bf(v.z); o.w = f2bf(v.w);
  }
  ((ushort4*)out)[(size_t)r * 736 + c4] = o;
}

// ------ transpose+convert: in f32 [Kin][Nd] -> out bf16 [Npad][Kout], zero-padded ------
__global__ __launch_bounds__(256) void k_transpose(const float* __restrict__ in,
                                                   u16* __restrict__ out,
                                                   int Kin, int Kout, int Nd, int Npad) {
  __shared__ float tile[32][33];
  int n0 = blockIdx.x * 32, k0 = blockIdx.y * 32;
  int c = threadIdx.x & 31, r0 = threadIdx.x >> 5;
#pragma unroll
  for (int j = 0; j < 4; j++) {
    int r = r0 + j * 8;
    float v = 0.f;
    if (n0 + c < Nd && k0 + r < Kin) v = in[(size_t)(k0 + r) * Nd + n0 + c];
    tile[r][c] = v;
  }
  __syncthreads();
#pragma unroll
  for (int j = 0; j < 4; j++) {
    int rr = r0 + j * 8;  // local n
    int n = n0 + rr;
    if (n < Npad) out[(size_t)n * Kout + k0 + c] = f2bf(tile[c][rr]);
  }
}

// ======== GEMM1: 256x256, BK=64, 8-phase fine-interleaved schedule ========
// A [2048][2944] bf16, B [5120][2944] bf16 (B^T), out qkv bf16 [2048][5120] + RoPE.
// LDS: 2 bufs x {A:[2kh][256r][32k], B:[2kh][256r][32k]} = 128 KiB.
// Iteration = 2 K-tiles = 8 phases; each phase: ds_reads + 1 half-tile stage +
// barrier + lgkm0 + 16 MFMA + barrier; vmcnt(4) at odd-phase ends (counted, T4).
__global__ __launch_bounds__(512, 1) void k_gemm1(const u16* __restrict__ Ag,
                                                  const u16* __restrict__ Bg,
                                                  const float* __restrict__ bias,
                                                  const float2* __restrict__ tab,
                                                  u16* __restrict__ C) {
  __shared__ u16 lds_[2][32768];
  u16* L = &lds_[0][0];
  const int tid = threadIdx.x;
  const int lane = tid & 63, wave = tid >> 6;
  const int wm = wave >> 2, wn = wave & 3;
  const int lr = lane & 15, lg = lane >> 4;
  int bid = blockIdx.x;
  int sb = (bid & 7) * 20 + (bid >> 3);  // 160 = 8 XCD x 20
  const int m0 = (sb / 20) * 256, n0 = (sb % 20) * 256;

  f32x4 acc[8][4] = {};
  bf16x8 Bf[4];

  const int srow = wave * 16 + (lane >> 2);                  // staging row (r*128 + srow)
  const int xsl = (((lane & 3) ^ ((lane >> 2) & 3)) << 3);   // pre-swizzled k-chunk (elems)
  const int rb = (lg * 16) ^ ((lr & 3) << 4);                // frag-read swizzled byte off

#define G1_STAGE_A(b, kh, kt)                                                   \
  { _Pragma("unroll") for (int r_ = 0; r_ < 2; r_++) {                          \
      gl_lds16(Ag + (size_t)(m0 + r_ * 128 + srow) * KPAD + (kt) + (kh) * 32 + xsl, \
               L + (b) * 32768 + (kh) * 8192 + (r_ * 128 + wave * 16) * 32); } }
#define G1_STAGE_B(b, kh, kt)                                                   \
  { _Pragma("unroll") for (int r_ = 0; r_ < 2; r_++) {                          \
      gl_lds16(Bg + (size_t)(n0 + r_ * 128 + srow) * KPAD + (kt) + (kh) * 32 + xsl, \
               L + (b) * 32768 + 16384 + (kh) * 8192 + (r_ * 128 + wave * 16) * 32); } }

#define VM4 asm volatile("s_waitcnt vmcnt(4)" ::: "memory");
#define VM0 asm volatile("s_waitcnt vmcnt(0)" ::: "memory");

#define PHASE(bb, kh, mh, LOADB, STAGE_STMT, WAIT_STMT)                         \
  {                                                                             \
    if (LOADB) {                                                                \
      _Pragma("unroll") for (int nf = 0; nf < 4; nf++)                          \
        Bf[nf] = fragrd(L + (bb) * 32768 + 16384 + (kh) * 8192,                 \
                        wn * 64 + nf * 16 + lr, rb);                            \
    }                                                                           \
    bf16x8 Af[4];                                                               \
    _Pragma("unroll") for (int mi = 0; mi < 4; mi++)                            \
      Af[mi] = fragrd(L + (bb) * 32768 + (kh) * 8192,                           \
                      wm * 128 + ((mh) * 4 + mi) * 16 + lr, rb);                \
    STAGE_STMT;                                                                 \
    WAIT_STMT;                                                                  \
    __builtin_amdgcn_s_barrier();                                               \
    asm volatile("s_waitcnt lgkmcnt(0)" ::: "memory");                          \
    __builtin_amdgcn_sched_barrier(0);                                          \
    __builtin_amdgcn_s_setprio(1);                                              \
    _Pragma("unroll") for (int mi = 0; mi < 4; mi++)                            \
      _Pragma("unroll") for (int nf = 0; nf < 4; nf++)                          \
        acc[(mh) * 4 + mi][nf] = MFMA16(Af[mi], Bf[nf], acc[(mh) * 4 + mi][nf]); \
    __builtin_amdgcn_s_setprio(0);                                              \
    __builtin_amdgcn_s_barrier();                                               \
  }

  // prologue: tile 0 (4 halves) -> buf0; first 2 halves certified resident
  G1_STAGE_A(0, 0, 0)
  G1_STAGE_B(0, 0, 0)
  G1_STAGE_A(0, 1, 0)
  G1_STAGE_B(0, 1, 0)
  VM4
  __builtin_amdgcn_s_barrier();

  // iteration: tiles 2i (buf0, phases 0-3) and 2i+1 (buf1, phases 4-7).
  // stages: phases 0-3 -> tile 2i+1 into buf1; phases 4-7 -> tile 2i+2 into buf0.
#define G1_ITER(ii, TAILV)                                                      \
  {                                                                             \
    const int ktB = (2 * (ii) + 1) * 64;                                        \
    const int ktC = (2 * (ii) + 2) * 64;                                        \
    PHASE(0, 0, 0, true,  { G1_STAGE_A(1, 0, ktB) }, {})                        \
    PHASE(0, 0, 1, false, { G1_STAGE_B(1, 0, ktB) }, VM4)                       \
    PHASE(0, 1, 0, true,  { G1_STAGE_A(1, 1, ktB) }, {})                        \
    PHASE(0, 1, 1, false, { G1_STAGE_B(1, 1, ktB) }, VM4)                       \
    PHASE(1, 0, 0, true,  { if (!(TAILV)) G1_STAGE_A(0, 0, ktC) }, {})          \
    PHASE(1, 0, 1, false, { if (!(TAILV)) G1_STAGE_B(0, 0, ktC) },              \
          { if (TAILV) { VM0 } else { VM4 } })                                  \
    PHASE(1, 1, 0, true,  { if (!(TAILV)) G1_STAGE_A(0, 1, ktC) }, {})          \
    PHASE(1, 1, 1, false, { if (!(TAILV)) G1_STAGE_B(0, 1, ktC) },              \
          { if (!(TAILV)) { VM4 } })                                            \
  }

  for (int i = 0; i < 22; i++) {
    G1_ITER(i, false)
  }
  G1_ITER(22, true)

#undef G1_ITER
#undef PHASE
#undef G1_STAGE_A
#undef G1_STAGE_B

  // ---- epilogue: bias (+ RoPE for Q/K cols), bf16 store ----
  const bool rope = (n0 < 4608);
  if (rope) {
#pragma unroll
    for (int mf = 0; mf < 8; mf++)
#pragma unroll
      for (int nf = 0; nf < 2; nf++) {
        int col1 = n0 + wn * 64 + nf * 16 + lr;
        int col2 = col1 + 32;
        float b1 = bias[col1], b2 = bias[col2];
#pragma unroll
        for (int rg = 0; rg < 4; rg++) {
          int row = m0 + wm * 128 + mf * 16 + lg * 4 + rg;
          float2 cs = tab[(size_t)row * 32 + nf * 16 + lr];
          float x1 = acc[mf][nf][rg] + b1;
          float x2 = acc[mf][nf + 2][rg] + b2;
          C[(size_t)row * QKV_N + col1] = f2bf(x1 * cs.x - x2 * cs.y);
          C[(size_t)row * QKV_N + col2] = f2bf(x2 * cs.x + x1 * cs.y);
        }
      }
  } else {
#pragma unroll
    for (int mf = 0; mf < 8; mf++)
#pragma unroll
      for (int nf = 0; nf < 4; nf++) {
        int col = n0 + wn * 64 + nf * 16 + lr;
        float bv = bias[col];
#pragma unroll
        for (int rg = 0; rg < 4; rg++) {
          int row = m0 + wm * 128 + mf * 16 + lg * 4 + rg;
          C[(size_t)row * QKV_N + col] = f2bf(acc[mf][nf][rg] + bv);
        }
      }
  }
}

// ======== GEMM2: 128x128, BK=64, 2-tile ring, counted vmcnt (round-5 structure) ========
// A = attn bf16 [2048][4096], B = woT bf16 [2944][4096], C f32 [2048][2880].
__global__ __launch_bounds__(256, 2) void k_gemm2(const u16* __restrict__ Ag,
                                                  const u16* __restrict__ Bg,
                                                  const float* __restrict__ bias,
                                                  float* __restrict__ C) {
  __shared__ u16 ldsbuf[2][16384];  // [buf][A 8192 | B 8192]
  const int tid = threadIdx.x;
  const int lane = tid & 63, wave = tid >> 6;
  const int wm = wave >> 1, wn = wave & 1;
  const int lr = lane & 15, lg = lane >> 4;
  int bid = blockIdx.x;
  int sb = (bid & 7) * 46 + (bid >> 3);  // 368 = 8 XCD x 46
  const int m0 = (sb / 23) * 128, n0 = (sb % 23) * 128;

  f32x4 acc[4][4] = {};

  const int srow = wave * 8 + (lane >> 3);         // within 32-row round
  const int sc = ((lane & 7) ^ (lane >> 3)) << 3;  // pre-swizzled chunk
  const u16* gA = Ag + (size_t)(m0 + srow) * ATTN_K + sc;
  const u16* gB = Bg + (size_t)(n0 + srow) * ATTN_K + sc;

#define G2_STAGE(kt, b)                                                          \
  {                                                                              \
    u16* Ab = &ldsbuf[b][0];                                                     \
    u16* Bb = &ldsbuf[b][8192];                                                  \
    _Pragma("unroll") for (int r = 0; r < 4; r++) {                              \
      gl_lds16(gA + (size_t)(r * 32) * ATTN_K + (kt), Ab + (r * 32 + wave * 8) * 64); \
      gl_lds16(gB + (size_t)(r * 32) * ATTN_K + (kt), Bb + (r * 32 + wave * 8) * 64); \
    }                                                                            \
  }

  G2_STAGE(0, 0)
  G2_STAGE(64, 1)
  asm volatile("s_waitcnt vmcnt(8)" ::: "memory");
  __builtin_amdgcn_s_barrier();

  for (int t = 0; t < 64; t++) {
    const int b = t & 1;
    const u16* La = &ldsbuf[b][0];
    const u16* Lb = &ldsbuf[b][8192];
    bf16x8 Bf[4][2];
#pragma unroll
    for (int nf = 0; nf < 4; nf++)
#pragma unroll
      for (int kh = 0; kh < 2; kh++)
        Bf[nf][kh] = lds_frag(Lb, wn * 64 + nf * 16 + lr, kh, lg);
    bf16x8 Af[2][2];
#pragma unroll
    for (int mi = 0; mi < 2; mi++)
#pragma unroll
      for (int kh = 0; kh < 2; kh++)
        Af[mi][kh] = lds_frag(La, wm * 64 + mi * 16 + lr, kh, lg);
#pragma unroll
    for (int q = 0; q < 2; q++) {
      bf16x8 An[2][2];
      if (q < 1) {
#pragma unroll
        for (int mi = 0; mi < 2; mi++)
#pragma unroll
          for (int kh = 0; kh < 2; kh++)
            An[mi][kh] = lds_frag(La, wm * 64 + ((q + 1) * 2 + mi) * 16 + lr, kh, lg);
      }
      __builtin_amdgcn_s_setprio(1);
#pragma unroll
      for (int mi = 0; mi < 2; mi++)
#pragma unroll
        for (int nf = 0; nf < 4; nf++)
#pragma unroll
          for (int kh = 0; kh < 2; kh++)
            acc[q * 2 + mi][nf] = MFMA16(Af[mi][kh], Bf[nf][kh], acc[q * 2 + mi][nf]);
      __builtin_amdgcn_s_setprio(0);
      if (q < 1) {
#pragma unroll
        for (int mi = 0; mi < 2; mi++)
#pragma unroll
          for (int kh = 0; kh < 2; kh++)
            Af[mi][kh] = An[mi][kh];
      }
    }
    __builtin_amdgcn_s_barrier();
    if (t <= 61) {
      G2_STAGE((t + 2) * 64, b)
      asm volatile("s_waitcnt vmcnt(8)" ::: "memory");
    } else {
      asm volatile("s_waitcnt vmcnt(0)" ::: "memory");
    }
    __builtin_amdgcn_s_barrier();
  }
#undef G2_STAGE

#pragma unroll
  for (int mi = 0; mi < 4; mi++)
#pragma unroll
    for (int ni = 0; ni < 4; ni++) {
      int row = m0 + wm * 64 + mi * 16 + lg * 4;
      int col = n0 + wn * 64 + ni * 16 + lr;
      if (col < 2880) {
        float bv = bias[col];
#pragma unroll
        for (int rg = 0; rg < 4; rg++)
          C[(size_t)(row + rg) * 2880 + col] = acc[mi][ni][rg] + bv;
      }
    }
}

// ---------------- sliding-window attention with sinks (bf16 qkv input) ----------------
__global__ __launch_bounds__(512, 2) void k_attn(const u16* __restrict__ qkv,
                                                 const float* __restrict__ sinks,
                                                 u16* __restrict__ out) {
  __shared__ u16 Klds[160 * 64];
  __shared__ u16 Vt[64 * 168];
  __shared__ u16 Pslab[8 * 32 * 40];
  const int hk = blockIdx.y;
  const int s0 = blockIdx.x * 32;
  const int kb = s0 - 127;
  const int tid = threadIdx.x;
  const int lane = tid & 63, w = tid >> 6;
  const int lr = lane & 15, lg = lane >> 4;

  for (int ch = tid; ch < 160 * 8; ch += 512) {
    int key = ch >> 3, c = ch & 7;
    int kidx = kb + key;
    u16x8 val = {0, 0, 0, 0, 0, 0, 0, 0};
    if (kidx >= 0 && kidx < SEQ)
      val = *(const u16x8*)(qkv + (size_t)kidx * QKV_N + 4096 + hk * 64 + c * 8);
    int off = (key * 128 + c * 16) ^ ((key & 7) << 4);
    *(u16x8*)((char*)Klds + off) = val;
  }
  for (int e4 = tid; e4 < 160 * 16; e4 += 512) {
    int key = e4 >> 4, d0 = (e4 & 15) * 4;
    int kidx = kb + key;
    ushort4 v = {0, 0, 0, 0};
    if (kidx >= 0 && kidx < SEQ)
      v = *(const ushort4*)(qkv + (size_t)kidx * QKV_N + 4608 + hk * 64 + d0);
    Vt[(d0 + 0) * 168 + key] = v.x;
    Vt[(d0 + 1) * 168 + key] = v.y;
    Vt[(d0 + 2) * 168 + key] = v.z;
    Vt[(d0 + 3) * 168 + key] = v.w;
  }

  const int head = hk * 8 + w;
  bf16x8 qf[2][2];
#pragma unroll
  for (int rt = 0; rt < 2; rt++)
#pragma unroll
    for (int ks = 0; ks < 2; ks++)
      qf[rt][ks] = *(const bf16x8*)(qkv + (size_t)(s0 + rt * 16 + lr) * QKV_N +
                                    head * 64 + ks * 32 + lg * 8);
  __syncthreads();

  f32x4 sc[2][10];
  f32x4 zz = {0.f, 0.f, 0.f, 0.f};
#pragma unroll
  for (int rt = 0; rt < 2; rt++)
#pragma unroll
    for (int nt = 0; nt < 10; nt++) sc[rt][nt] = zz;
#pragma unroll
  for (int nt = 0; nt < 10; nt++) {
    int key = nt * 16 + lr;
#pragma unroll
    for (int ks = 0; ks < 2; ks++) {
      int off = (key * 128 + ks * 64 + lg * 16) ^ ((key & 7) << 4);
      bf16x8 kf = *(const bf16x8*)((const char*)Klds + off);
      sc[0][nt] = MFMA16(qf[0][ks], kf, sc[0][nt]);
      sc[1][nt] = MFMA16(qf[1][ks], kf, sc[1][nt]);
    }
  }

#pragma unroll
  for (int rt = 0; rt < 2; rt++)
#pragma unroll
    for (int nt = 0; nt < 10; nt++)
#pragma unroll
      for (int rg = 0; rg < 4; rg++) {
        int qq = rt * 16 + lg * 4 + rg;
        int j = nt * 16 + lr;
        bool valid = (j >= qq) && (j <= qq + 127) && ((kb + j) >= 0);
        sc[rt][nt][rg] = valid ? sc[rt][nt][rg] * SCALE : NEGINF;
      }

  const float sink = sinks[head];
  float den[2][4];
#pragma unroll
  for (int rt = 0; rt < 2; rt++)
#pragma unroll
    for (int rg = 0; rg < 4; rg++) {
      float m = NEGINF;
#pragma unroll
      for (int nt = 0; nt < 10; nt++) m = fmaxf(m, sc[rt][nt][rg]);
#pragma unroll
      for (int x = 1; x < 16; x <<= 1) m = fmaxf(m, __shfl_xor(m, x, 64));
      m = fmaxf(m, sink);
      float sum = 0.f;
#pragma unroll
      for (int nt = 0; nt < 10; nt++) {
        float p = __expf(sc[rt][nt][rg] - m);
        sc[rt][nt][rg] = p;
        sum += p;
      }
#pragma unroll
      for (int x = 1; x < 16; x <<= 1) sum += __shfl_xor(sum, x, 64);
      den[rt][rg] = sum + __expf(sink - m);
    }

  f32x4 oacc[2][4];
#pragma unroll
  for (int rt = 0; rt < 2; rt++)
#pragma unroll
    for (int dn = 0; dn < 4; dn++) oacc[rt][dn] = zz;
  u16* slab = &Pslab[w * 32 * 40];
#pragma unroll
  for (int kt = 0; kt < 5; kt++) {
#pragma unroll
    for (int rt = 0; rt < 2; rt++)
#pragma unroll
      for (int j2 = 0; j2 < 2; j2++)
#pragma unroll
        for (int rg = 0; rg < 4; rg++)
          slab[(rt * 16 + lg * 4 + rg) * 40 + j2 * 16 + lr] = f2bf(sc[rt][kt * 2 + j2][rg]);
    asm volatile("s_waitcnt lgkmcnt(0)" ::: "memory");
    __builtin_amdgcn_sched_barrier(0);
    bf16x8 pf0 = *(const bf16x8*)&slab[lr * 40 + lg * 8];
    bf16x8 pf1 = *(const bf16x8*)&slab[(16 + lr) * 40 + lg * 8];
#pragma unroll
    for (int dn = 0; dn < 4; dn++) {
      bf16x8 vf = *(const bf16x8*)&Vt[(dn * 16 + lr) * 168 + kt * 32 + lg * 8];
      oacc[0][dn] = MFMA16(pf0, vf, oacc[0][dn]);
      oacc[1][dn] = MFMA16(pf1, vf, oacc[1][dn]);
    }
  }

#pragma unroll
  for (int rt = 0; rt < 2; rt++)
#pragma unroll
    for (int dn = 0; dn < 4; dn++)
#pragma unroll
      for (int rg = 0; rg < 4; rg++) {
        int s = s0 + rt * 16 + lg * 4 + rg;
        float val = oacc[rt][dn][rg] / den[rt][rg];
        out[(size_t)s * ATTN_K + head * 64 + dn * 16 + lr] = f2bf(val);
      }
}

extern "C" void kernel_launch(void* const* d_in, const int* in_sizes, int n_in,
                              void* d_out, int out_size, void* d_ws, size_t ws_size,
                              hipStream_t stream) {
  const float* hs = (const float*)d_in[0];
  const int* pos = (const int*)d_in[1];
  const float* wqkv = (const float*)d_in[2];
  const float* bqkv = (const float*)d_in[3];
  const float* wo = (const float*)d_in[4];
  const float* bo = (const float*)d_in[5];
  const float* sinks = (const float*)d_in[6];
  float* out = (float*)d_out;

  char* ws = (char*)d_ws;
  u16* qkvb = (u16*)(ws + 0);               // 2048*5120*2 = 20,971,520 (bf16)
  u16* hsb = (u16*)(ws + 41943040);         // 2048*2944*2 = 12,058,624
  u16* wqkvT = (u16*)(ws + 54001664);       // 5120*2944*2 = 30,146,560 -> ends 84,148,224
  u16* attnb = (u16*)(ws + 41943040);       // 2048*4096*2 (aliases dead hsb/wqkvT)
  u16* woT = (u16*)(ws + 84148224);         // 2944*4096*2 = 24,117,248 -> ends 108,265,472
  float2* tab = (float2*)(ws + 108265472);  // 2048*32*8   = 524,288

  k_rope_table<<<256, 256, 0, stream>>>(pos, tab);
  k_convert_pad<<<5888, 256, 0, stream>>>(hs, hsb);
  k_transpose<<<dim3(160, 92), 256, 0, stream>>>(wqkv, wqkvT, 2880, KPAD, 5120, 5120);
  k_transpose<<<dim3(92, 128), 256, 0, stream>>>(wo, woT, 4096, 4096, 2880, 2944);
  k_gemm1<<<160, 512, 0, stream>>>(hsb, wqkvT, bqkv, tab, qkvb);
  k_attn<<<dim3(64, 8), 512, 0, stream>>>(qkvb, sinks, attnb);
  k_gemm2<<<368, 256, 0, stream>>>(attnb, woT, bo, out);
}

// Round 7
// 202.192 us; speedup vs baseline: 1.1140x; 1.0400x over previous
//
#include <hip/hip_runtime.h>

typedef unsigned short u16;
typedef __bf16 bf16x8 __attribute__((ext_vector_type(8)));
typedef float f32x4 __attribute__((ext_vector_type(4)));
typedef unsigned short u16x8 __attribute__((ext_vector_type(8)));

#define QKV_N 5120
#define SEQ 2048
#define ATTN_K 4096
#define KPAD 2944   // 2880 padded to 46*64
#define SCALE 0.125f
#define NEGINF -1e30f

__device__ __forceinline__ u16 f2bf(float f) {
  unsigned int u = __builtin_bit_cast(unsigned int, f);
  u = (u + 0x7FFFu + ((u >> 16) & 1u)) >> 16;
  return (u16)u;
}

#define MFMA16(a, b, c) __builtin_amdgcn_mfma_f32_16x16x32_bf16((a), (b), (c), 0, 0, 0)

// async global->LDS, 16B per lane; LDS dest = wave-uniform base + lane*16
__device__ __forceinline__ void gl_lds16(const u16* g, u16* l) {
  __builtin_amdgcn_global_load_lds(
      (const __attribute__((address_space(1))) unsigned int*)(const void*)g,
      (__attribute__((address_space(3))) unsigned int*)(void*)l, 16, 0, 0);
}

// fragment read from [rows][32k] half-tile (64B rows).
// Bank period = 2 rows, so swizzle key is (row>>1)&3: slot = lg ^ ((row>>1)&3).
__device__ __forceinline__ bf16x8 fragrd(const u16* base, int row, int rb) {
  return *(const bf16x8*)((const char*)(base + row * 32) + rb);
}

// legacy frag read for GEMM2's [rows][64k] swizzled tile (128B rows)
__device__ __forceinline__ bf16x8 lds_frag(const u16* mat, int row, int kh, int lg) {
  int off = row * 128 + ((kh * 64 + lg * 16) ^ ((row & 7) << 4));
  return *(const bf16x8*)((const char*)mat + off);
}

// ---------------- RoPE table: tab[s*32+i] = {cos, sin} ----------------
__global__ __launch_bounds__(256) void k_rope_table(const int* __restrict__ pos,
                                                    float2* __restrict__ tab) {
  int t = blockIdx.x * 256 + threadIdx.x;  // 65536 = 2048*32
  int s = t >> 5, i = t & 31;
  float freq = powf(150000.0f, -(float)i * (1.0f / 32.0f));
  float ang = (float)pos[s] * freq;
  float sv, cv;
  sincosf(ang, &sv, &cv);
  tab[t] = make_float2(cv, sv);
}

// ---------------- f32 -> bf16 convert with K-pad: out [2048][2944] ----------------
__global__ __launch_bounds__(256) void k_convert_pad(const float* __restrict__ in,
                                                     u16* __restrict__ out) {
  int i = blockIdx.x * 256 + threadIdx.x;  // per 4 out elems; 2048*736 total
  int r = i / 736, c4 = i - r * 736;
  if (r >= 2048) return;
  ushort4 o = {0, 0, 0, 0};
  if (c4 < 720) {
    float4 v = *(const float4*)(in + (size_t)r * 2880 + c4 * 4);
    o.x = f2bf(v.x); o.y = f2bf(v.y); o.z = f2bf(v.z); o.w = f2bf(v.w);
  }
  ((ushort4*)out)[(size_t)r * 736 + c4] = o;
}

// ------ transpose+convert: in f32 [Kin][Nd] -> out bf16 [Npad][Kout], zero-padded ------
__global__ __launch_bounds__(256) void k_transpose(const float* __restrict__ in,
                                                   u16* __restrict__ out,
                                                   int Kin, int Kout, int Nd, int Npad) {
  __shared__ float tile[32][33];
  int n0 = blockIdx.x * 32, k0 = blockIdx.y * 32;
  int c = threadIdx.x & 31, r0 = threadIdx.x >> 5;
#pragma unroll
  for (int j = 0; j < 4; j++) {
    int r = r0 + j * 8;
    float v = 0.f;
    if (n0 + c < Nd && k0 + r < Kin) v = in[(size_t)(k0 + r) * Nd + n0 + c];
    tile[r][c] = v;
  }
  __syncthreads();
#pragma unroll
  for (int j = 0; j < 4; j++) {
    int rr = r0 + j * 8;  // local n
    int n = n0 + rr;
    if (n < Npad) out[(size_t)n * Kout + k0 + c] = f2bf(tile[c][rr]);
  }
}

// ======== GEMM1: 256x256, BK=64, 8-phase fine-interleaved schedule ========
// A [2048][2944] bf16, B [5120][2944] bf16 (B^T), out qkv bf16 [2048][5120] + RoPE.
// LDS: 2 bufs x {A:[2kh][256r][32k], B:[2kh][256r][32k]} = 128 KiB.
// Phase: ds_reads + 1 half-tile stage + [vmcnt(4)] + barrier + MFMA + barrier.
// No forced lgkm drain: compiler emits fine-grained lgkmcnt before each MFMA
// consumer; buffer lifecycle is ordered by the vmcnt asm fences + barriers.
__global__ __launch_bounds__(512, 1) void k_gemm1(const u16* __restrict__ Ag,
                                                  const u16* __restrict__ Bg,
                                                  const float* __restrict__ bias,
                                                  const float2* __restrict__ tab,
                                                  u16* __restrict__ C) {
  __shared__ u16 lds_[2][32768];
  u16* L = &lds_[0][0];
  const int tid = threadIdx.x;
  const int lane = tid & 63, wave = tid >> 6;
  const int wm = wave >> 2, wn = wave & 3;
  const int lr = lane & 15, lg = lane >> 4;
  int bid = blockIdx.x;
  int sb = (bid & 7) * 20 + (bid >> 3);  // 160 = 8 XCD x 20
  const int m0 = (sb / 20) * 256, n0 = (sb % 20) * 256;

  f32x4 acc[8][4] = {};
  bf16x8 Bf[4];

  const int srow = wave * 16 + (lane >> 2);                 // staging row (r*128 + srow)
  const int xsl = (((lane & 3) ^ ((lane >> 3) & 3)) << 3);  // pre-swz k-chunk: key (row>>1)&3
  const int rb = (lg * 16) ^ (((lr >> 1) & 3) << 4);        // frag-read swz byte off

#define G1_STAGE_A(b, kh, kt)                                                   \
  { _Pragma("unroll") for (int r_ = 0; r_ < 2; r_++) {                          \
      gl_lds16(Ag + (size_t)(m0 + r_ * 128 + srow) * KPAD + (kt) + (kh) * 32 + xsl, \
               L + (b) * 32768 + (kh) * 8192 + (r_ * 128 + wave * 16) * 32); } }
#define G1_STAGE_B(b, kh, kt)                                                   \
  { _Pragma("unroll") for (int r_ = 0; r_ < 2; r_++) {                          \
      gl_lds16(Bg + (size_t)(n0 + r_ * 128 + srow) * KPAD + (kt) + (kh) * 32 + xsl, \
               L + (b) * 32768 + 16384 + (kh) * 8192 + (r_ * 128 + wave * 16) * 32); } }

#define VM4 asm volatile("s_waitcnt vmcnt(4)" ::: "memory");
#define VM0 asm volatile("s_waitcnt vmcnt(0)" ::: "memory");

#define PHASE(bb, kh, mh, LOADB, STAGE_STMT, WAIT_STMT)                         \
  {                                                                             \
    if (LOADB) {                                                                \
      _Pragma("unroll") for (int nf = 0; nf < 4; nf++)                          \
        Bf[nf] = fragrd(L + (bb) * 32768 + 16384 + (kh) * 8192,                 \
                        wn * 64 + nf * 16 + lr, rb);                            \
    }                                                                           \
    bf16x8 Af[4];                                                               \
    _Pragma("unroll") for (int mi = 0; mi < 4; mi++)                            \
      Af[mi] = fragrd(L + (bb) * 32768 + (kh) * 8192,                           \
                      wm * 128 + ((mh) * 4 + mi) * 16 + lr, rb);                \
    STAGE_STMT;                                                                 \
    WAIT_STMT;                                                                  \
    __builtin_amdgcn_s_barrier();                                               \
    __builtin_amdgcn_s_setprio(1);                                              \
    _Pragma("unroll") for (int mi = 0; mi < 4; mi++)                            \
      _Pragma("unroll") for (int nf = 0; nf < 4; nf++)                          \
        acc[(mh) * 4 + mi][nf] = MFMA16(Af[mi], Bf[nf], acc[(mh) * 4 + mi][nf]); \
    __builtin_amdgcn_s_setprio(0);                                              \
    __builtin_amdgcn_s_barrier();                                               \
  }

  // prologue: tile 0 (4 halves) -> buf0; first 2 halves certified resident
  G1_STAGE_A(0, 0, 0)
  G1_STAGE_B(0, 0, 0)
  G1_STAGE_A(0, 1, 0)
  G1_STAGE_B(0, 1, 0)
  VM4
  __builtin_amdgcn_s_barrier();

  // iteration: tiles 2i (buf0, phases 0-3) and 2i+1 (buf1, phases 4-7).
  // stages: phases 0-3 -> tile 2i+1 into buf1; phases 4-7 -> tile 2i+2 into buf0.
#define G1_ITER(ii, TAILV)                                                      \
  {                                                                             \
    const int ktB = (2 * (ii) + 1) * 64;                                        \
    const int ktC = (2 * (ii) + 2) * 64;                                        \
    PHASE(0, 0, 0, true,  { G1_STAGE_A(1, 0, ktB) }, {})                        \
    PHASE(0, 0, 1, false, { G1_STAGE_B(1, 0, ktB) }, VM4)                       \
    PHASE(0, 1, 0, true,  { G1_STAGE_A(1, 1, ktB) }, {})                        \
    PHASE(0, 1, 1, false, { G1_STAGE_B(1, 1, ktB) }, VM4)                       \
    PHASE(1, 0, 0, true,  { if (!(TAILV)) G1_STAGE_A(0, 0, ktC) }, {})          \
    PHASE(1, 0, 1, false, { if (!(TAILV)) G1_STAGE_B(0, 0, ktC) },              \
          { if (TAILV) { VM0 } else { VM4 } })                                  \
    PHASE(1, 1, 0, true,  { if (!(TAILV)) G1_STAGE_A(0, 1, ktC) }, {})          \
    PHASE(1, 1, 1, false, { if (!(TAILV)) G1_STAGE_B(0, 1, ktC) },              \
          { if (!(TAILV)) { VM4 } })                                            \
  }

  for (int i = 0; i < 22; i++) {
    G1_ITER(i, false)
  }
  G1_ITER(22, true)

#undef G1_ITER
#undef PHASE
#undef G1_STAGE_A
#undef G1_STAGE_B

  // ---- epilogue: bias (+ RoPE for Q/K cols), bf16 store ----
  const bool rope = (n0 < 4608);
  if (rope) {
#pragma unroll
    for (int mf = 0; mf < 8; mf++)
#pragma unroll
      for (int nf = 0; nf < 2; nf++) {
        int col1 = n0 + wn * 64 + nf * 16 + lr;
        int col2 = col1 + 32;
        float b1 = bias[col1], b2 = bias[col2];
#pragma unroll
        for (int rg = 0; rg < 4; rg++) {
          int row = m0 + wm * 128 + mf * 16 + lg * 4 + rg;
          float2 cs = tab[(size_t)row * 32 + nf * 16 + lr];
          float x1 = acc[mf][nf][rg] + b1;
          float x2 = acc[mf][nf + 2][rg] + b2;
          C[(size_t)row * QKV_N + col1] = f2bf(x1 * cs.x - x2 * cs.y);
          C[(size_t)row * QKV_N + col2] = f2bf(x2 * cs.x + x1 * cs.y);
        }
      }
  } else {
#pragma unroll
    for (int mf = 0; mf < 8; mf++)
#pragma unroll
      for (int nf = 0; nf < 4; nf++) {
        int col = n0 + wn * 64 + nf * 16 + lr;
        float bv = bias[col];
#pragma unroll
        for (int rg = 0; rg < 4; rg++) {
          int row = m0 + wm * 128 + mf * 16 + lg * 4 + rg;
          C[(size_t)row * QKV_N + col] = f2bf(acc[mf][nf][rg] + bv);
        }
      }
  }
}

// ======== GEMM2: 128x128, BK=64, 2-tile ring, counted vmcnt (round-5 structure) ========
// A = attn bf16 [2048][4096], B = woT bf16 [2944][4096], C f32 [2048][2880].
__global__ __launch_bounds__(256, 2) void k_gemm2(const u16* __restrict__ Ag,
                                                  const u16* __restrict__ Bg,
                                                  const float* __restrict__ bias,
                                                  float* __restrict__ C) {
  __shared__ u16 ldsbuf[2][16384];  // [buf][A 8192 | B 8192]
  const int tid = threadIdx.x;
  const int lane = tid & 63, wave = tid >> 6;
  const int wm = wave >> 1, wn = wave & 1;
  const int lr = lane & 15, lg = lane >> 4;
  int bid = blockIdx.x;
  int sb = (bid & 7) * 46 + (bid >> 3);  // 368 = 8 XCD x 46
  const int m0 = (sb / 23) * 128, n0 = (sb % 23) * 128;

  f32x4 acc[4][4] = {};

  const int srow = wave * 8 + (lane >> 3);         // within 32-row round
  const int sc = ((lane & 7) ^ (lane >> 3)) << 3;  // pre-swizzled chunk
  const u16* gA = Ag + (size_t)(m0 + srow) * ATTN_K + sc;
  const u16* gB = Bg + (size_t)(n0 + srow) * ATTN_K + sc;

#define G2_STAGE(kt, b)                                                          \
  {                                                                              \
    u16* Ab = &ldsbuf[b][0];                                                     \
    u16* Bb = &ldsbuf[b][8192];                                                  \
    _Pragma("unroll") for (int r = 0; r < 4; r++) {                              \
      gl_lds16(gA + (size_t)(r * 32) * ATTN_K + (kt), Ab + (r * 32 + wave * 8) * 64); \
      gl_lds16(gB + (size_t)(r * 32) * ATTN_K + (kt), Bb + (r * 32 + wave * 8) * 64); \
    }                                                                            \
  }

  G2_STAGE(0, 0)
  G2_STAGE(64, 1)
  asm volatile("s_waitcnt vmcnt(8)" ::: "memory");
  __builtin_amdgcn_s_barrier();

  for (int t = 0; t < 64; t++) {
    const int b = t & 1;
    const u16* La = &ldsbuf[b][0];
    const u16* Lb = &ldsbuf[b][8192];
    bf16x8 Bf[4][2];
#pragma unroll
    for (int nf = 0; nf < 4; nf++)
#pragma unroll
      for (int kh = 0; kh < 2; kh++)
        Bf[nf][kh] = lds_frag(Lb, wn * 64 + nf * 16 + lr, kh, lg);
    bf16x8 Af[2][2];
#pragma unroll
    for (int mi = 0; mi < 2; mi++)
#pragma unroll
      for (int kh = 0; kh < 2; kh++)
        Af[mi][kh] = lds_frag(La, wm * 64 + mi * 16 + lr, kh, lg);
#pragma unroll
    for (int q = 0; q < 2; q++) {
      bf16x8 An[2][2];
      if (q < 1) {
#pragma unroll
        for (int mi = 0; mi < 2; mi++)
#pragma unroll
          for (int kh = 0; kh < 2; kh++)
            An[mi][kh] = lds_frag(La, wm * 64 + ((q + 1) * 2 + mi) * 16 + lr, kh, lg);
      }
      __builtin_amdgcn_s_setprio(1);
#pragma unroll
      for (int mi = 0; mi < 2; mi++)
#pragma unroll
        for (int nf = 0; nf < 4; nf++)
#pragma unroll
          for (int kh = 0; kh < 2; kh++)
            acc[q * 2 + mi][nf] = MFMA16(Af[mi][kh], Bf[nf][kh], acc[q * 2 + mi][nf]);
      __builtin_amdgcn_s_setprio(0);
      if (q < 1) {
#pragma unroll
        for (int mi = 0; mi < 2; mi++)
#pragma unroll
          for (int kh = 0; kh < 2; kh++)
            Af[mi][kh] = An[mi][kh];
      }
    }
    __builtin_amdgcn_s_barrier();
    if (t <= 61) {
      G2_STAGE((t + 2) * 64, b)
      asm volatile("s_waitcnt vmcnt(8)" ::: "memory");
    } else {
      asm volatile("s_waitcnt vmcnt(0)" ::: "memory");
    }
    __builtin_amdgcn_s_barrier();
  }
#undef G2_STAGE

#pragma unroll
  for (int mi = 0; mi < 4; mi++)
#pragma unroll
    for (int ni = 0; ni < 4; ni++) {
      int row = m0 + wm * 64 + mi * 16 + lg * 4;
      int col = n0 + wn * 64 + ni * 16 + lr;
      if (col < 2880) {
        float bv = bias[col];
#pragma unroll
        for (int rg = 0; rg < 4; rg++)
          C[(size_t)(row + rg) * 2880 + col] = acc[mi][ni][rg] + bv;
      }
    }
}

// ---------------- sliding-window attention with sinks (bf16 qkv input) ----------------
__global__ __launch_bounds__(512, 2) void k_attn(const u16* __restrict__ qkv,
                                                 const float* __restrict__ sinks,
                                                 u16* __restrict__ out) {
  __shared__ u16 Klds[160 * 64];
  __shared__ u16 Vt[64 * 168];
  __shared__ u16 Pslab[8 * 32 * 40];
  const int hk = blockIdx.y;
  const int s0 = blockIdx.x * 32;
  const int kb = s0 - 127;
  const int tid = threadIdx.x;
  const int lane = tid & 63, w = tid >> 6;
  const int lr = lane & 15, lg = lane >> 4;

  for (int ch = tid; ch < 160 * 8; ch += 512) {
    int key = ch >> 3, c = ch & 7;
    int kidx = kb + key;
    u16x8 val = {0, 0, 0, 0, 0, 0, 0, 0};
    if (kidx >= 0 && kidx < SEQ)
      val = *(const u16x8*)(qkv + (size_t)kidx * QKV_N + 4096 + hk * 64 + c * 8);
    int off = (key * 128 + c * 16) ^ ((key & 7) << 4);
    *(u16x8*)((char*)Klds + off) = val;
  }
  for (int e4 = tid; e4 < 160 * 16; e4 += 512) {
    int key = e4 >> 4, d0 = (e4 & 15) * 4;
    int kidx = kb + key;
    ushort4 v = {0, 0, 0, 0};
    if (kidx >= 0 && kidx < SEQ)
      v = *(const ushort4*)(qkv + (size_t)kidx * QKV_N + 4608 + hk * 64 + d0);
    Vt[(d0 + 0) * 168 + key] = v.x;
    Vt[(d0 + 1) * 168 + key] = v.y;
    Vt[(d0 + 2) * 168 + key] = v.z;
    Vt[(d0 + 3) * 168 + key] = v.w;
  }

  const int head = hk * 8 + w;
  bf16x8 qf[2][2];
#pragma unroll
  for (int rt = 0; rt < 2; rt++)
#pragma unroll
    for (int ks = 0; ks < 2; ks++)
      qf[rt][ks] = *(const bf16x8*)(qkv + (size_t)(s0 + rt * 16 + lr) * QKV_N +
                                    head * 64 + ks * 32 + lg * 8);
  __syncthreads();

  f32x4 sc[2][10];
  f32x4 zz = {0.f, 0.f, 0.f, 0.f};
#pragma unroll
  for (int rt = 0; rt < 2; rt++)
#pragma unroll
    for (int nt = 0; nt < 10; nt++) sc[rt][nt] = zz;
#pragma unroll
  for (int nt = 0; nt < 10; nt++) {
    int key = nt * 16 + lr;
#pragma unroll
    for (int ks = 0; ks < 2; ks++) {
      int off = (key * 128 + ks * 64 + lg * 16) ^ ((key & 7) << 4);
      bf16x8 kf = *(const bf16x8*)((const char*)Klds + off);
      sc[0][nt] = MFMA16(qf[0][ks], kf, sc[0][nt]);
      sc[1][nt] = MFMA16(qf[1][ks], kf, sc[1][nt]);
    }
  }

#pragma unroll
  for (int rt = 0; rt < 2; rt++)
#pragma unroll
    for (int nt = 0; nt < 10; nt++)
#pragma unroll
      for (int rg = 0; rg < 4; rg++) {
        int qq = rt * 16 + lg * 4 + rg;
        int j = nt * 16 + lr;
        bool valid = (j >= qq) && (j <= qq + 127) && ((kb + j) >= 0);
        sc[rt][nt][rg] = valid ? sc[rt][nt][rg] * SCALE : NEGINF;
      }

  const float sink = sinks[head];
  float den[2][4];
#pragma unroll
  for (int rt = 0; rt < 2; rt++)
#pragma unroll
    for (int rg = 0; rg < 4; rg++) {
      float m = NEGINF;
#pragma unroll
      for (int nt = 0; nt < 10; nt++) m = fmaxf(m, sc[rt][nt][rg]);
#pragma unroll
      for (int x = 1; x < 16; x <<= 1) m = fmaxf(m, __shfl_xor(m, x, 64));
      m = fmaxf(m, sink);
      float sum = 0.f;
#pragma unroll
      for (int nt = 0; nt < 10; nt++) {
        float p = __expf(sc[rt][nt][rg] - m);
        sc[rt][nt][rg] = p;
        sum += p;
      }
#pragma unroll
      for (int x = 1; x < 16; x <<= 1) sum += __shfl_xor(sum, x, 64);
      den[rt][rg] = sum + __expf(sink - m);
    }

  f32x4 oacc[2][4];
#pragma unroll
  for (int rt = 0; rt < 2; rt++)
#pragma unroll
    for (int dn = 0; dn < 4; dn++) oacc[rt][dn] = zz;
  u16* slab = &Pslab[w * 32 * 40];
#pragma unroll
  for (int kt = 0; kt < 5; kt++) {
#pragma unroll
    for (int rt = 0; rt < 2; rt++)
#pragma unroll
      for (int j2 = 0; j2 < 2; j2++)
#pragma unroll
        for (int rg = 0; rg < 4; rg++)
          slab[(rt * 16 + lg * 4 + rg) * 40 + j2 * 16 + lr] = f2bf(sc[rt][kt * 2 + j2][rg]);
    asm volatile("s_waitcnt lgkmcnt(0)" ::: "memory");
    __builtin_amdgcn_sched_barrier(0);
    bf16x8 pf0 = *(const bf16x8*)&slab[lr * 40 + lg * 8];
    bf16x8 pf1 = *(const bf16x8*)&slab[(16 + lr) * 40 + lg * 8];
#pragma unroll
    for (int dn = 0; dn < 4; dn++) {
      bf16x8 vf = *(const bf16x8*)&Vt[(dn * 16 + lr) * 168 + kt * 32 + lg * 8];
      oacc[0][dn] = MFMA16(pf0, vf, oacc[0][dn]);
      oacc[1][dn] = MFMA16(pf1, vf, oacc[1][dn]);
    }
  }

#pragma unroll
  for (int rt = 0; rt < 2; rt++)
#pragma unroll
    for (int dn = 0; dn < 4; dn++)
#pragma unroll
      for (int rg = 0; rg < 4; rg++) {
        int s = s0 + rt * 16 + lg * 4 + rg;
        float val = oacc[rt][dn][rg] / den[rt][rg];
        out[(size_t)s * ATTN_K + head * 64 + dn * 16 + lr] = f2bf(val);
      }
}

extern "C" void kernel_launch(void* const* d_in, const int* in_sizes, int n_in,
                              void* d_out, int out_size, void* d_ws, size_t ws_size,
                              hipStream_t stream) {
  const float* hs = (const float*)d_in[0];
  const int* pos = (const int*)d_in[1];
  const float* wqkv = (const float*)d_in[2];
  const float* bqkv = (const float*)d_in[3];
  const float* wo = (const float*)d_in[4];
  const float* bo = (const float*)d_in[5];
  const float* sinks = (const float*)d_in[6];
  float* out = (float*)d_out;

  char* ws = (char*)d_ws;
  u16* qkvb = (u16*)(ws + 0);               // 2048*5120*2 = 20,971,520 (bf16)
  u16* hsb = (u16*)(ws + 41943040);         // 2048*2944*2 = 12,058,624
  u16* wqkvT = (u16*)(ws + 54001664);       // 5120*2944*2 = 30,146,560 -> ends 84,148,224
  u16* attnb = (u16*)(ws + 41943040);       // 2048*4096*2 (aliases dead hsb/wqkvT)
  u16* woT = (u16*)(ws + 84148224);         // 2944*4096*2 = 24,117,248 -> ends 108,265,472
  float2* tab = (float2*)(ws + 108265472);  // 2048*32*8   = 524,288

  k_rope_table<<<256, 256, 0, stream>>>(pos, tab);
  k_convert_pad<<<5888, 256, 0, stream>>>(hs, hsb);
  k_transpose<<<dim3(160, 92), 256, 0, stream>>>(wqkv, wqkvT, 2880, KPAD, 5120, 5120);
  k_transpose<<<dim3(92, 128), 256, 0, stream>>>(wo, woT, 4096, 4096, 2880, 2944);
  k_gemm1<<<160, 512, 0, stream>>>(hsb, wqkvT, bqkv, tab, qkvb);
  k_attn<<<dim3(64, 8), 512, 0, stream>>>(qkvb, sinks, attnb);
  k_gemm2<<<368, 256, 0, stream>>>(attnb, woT, bo, out);
}